// Round 7
// baseline (1390.419 us; speedup 1.0000x reference)
//
#include <hip/hip_runtime.h>
#include <math.h>

// ---------------------------------------------------------------------------
// VQ-VAE forward on MI355X — round 7: fixup restructured (wave-split-k f64).
//   g1: h1 = relu(x @ W1^T + b1)        [x,W1 hi/lo planes -> h1 hi/lo planes]
//   g2: z_e = h1 @ W2^T + b2            [planes -> f32 z_e output]
//   vq: MFMA dots + top-2 argmin + gap flag -> exact f64 fixup
//   g3: h3 = relu(z_q @ W3^T + b3)      [A from f32 z_q (convert), B plane]
//   g4: recon = sigmoid(h3 @ W4^T + b4) [planes -> f32 recon]
// Round-7 change: vq_fixup only. Old: 4 samples/block, per-thread serial W1
// row reads -> 1.2 GB uncoalesced L3 traffic, 1.3% VALUBusy, 311 us. New:
// 8 samples/block, wave-per-output with 64-lane k-split (coalesced W1),
// phase-aliased LDS (h1 | x -> Wemb+z), f64 end-to-end as before.
// ---------------------------------------------------------------------------

typedef short bf16x8 __attribute__((ext_vector_type(8)));
typedef short short8 __attribute__((ext_vector_type(8)));
typedef float f32x4  __attribute__((ext_vector_type(4)));

#define GAP_T 2e-4

__device__ __forceinline__ unsigned short f32_to_bf16_rn(float v) {
    union { float f; unsigned u; } c; c.f = v;
    unsigned r = c.u + 0x7FFFu + ((c.u >> 16) & 1u);
    return (unsigned short)(r >> 16);
}
__device__ __forceinline__ float bf16_bits_to_f32(unsigned short b) {
    union { unsigned u; float f; } c; c.u = ((unsigned)b) << 16;
    return c.f;
}
__device__ __forceinline__ void glds16(const short* g, short* l) {
    __builtin_amdgcn_global_load_lds(
        (const __attribute__((address_space(1))) unsigned int*)g,
        (__attribute__((address_space(3))) unsigned int*)l, 16, 0, 0);
}

// ===================== plane prep: weights (B operand) ======================
__global__ __launch_bounds__(256) void prep_wplanes(
    const float* __restrict__ Wsrc, int N, int K, int KT,
    short* __restrict__ hi, short* __restrict__ lo)
{
    const int kt = blockIdx.x % KT;
    const int nb = blockIdx.x / KT;
    const size_t tb = (size_t)blockIdx.x * 4096;
    for (int ci = threadIdx.x; ci < 512; ci += 256) {
        const int row = ci >> 2;
        const int sl  = ci & 3;
        const int k0  = ((sl ^ (row & 3)) << 3);
        const int n   = nb * 128 + row;
        const int kk  = kt * 32 + k0;
        float f[8];
        #pragma unroll
        for (int e = 0; e < 8; ++e)
            f[e] = (n < N && kk + e < K) ? Wsrc[(size_t)n * K + kk + e] : 0.f;
        short8 h, l;
        #pragma unroll
        for (int e = 0; e < 8; ++e) {
            const unsigned short hb = f32_to_bf16_rn(f[e]);
            h[e] = (short)hb;
            l[e] = (short)f32_to_bf16_rn(f[e] - bf16_bits_to_f32(hb));
        }
        *reinterpret_cast<short8*>(&hi[tb + ci * 8]) = h;
        if (lo) *reinterpret_cast<short8*>(&lo[tb + ci * 8]) = l;
    }
}

// ========================= plane prep: x (A operand) ========================
__global__ __launch_bounds__(256) void prep_xplanes(
    const float* __restrict__ x, short* __restrict__ hi, short* __restrict__ lo)
{
    const int kt = blockIdx.x % 96;
    const int mb = blockIdx.x / 96;
    const size_t tb = (size_t)blockIdx.x * 4096;
    for (int ci = threadIdx.x; ci < 512; ci += 256) {
        const int row = ci >> 2;
        const int sl  = ci & 3;
        const int k0  = ((sl ^ (row & 3)) << 3);
        const float* src = &x[(size_t)(mb * 128 + row) * 3072 + kt * 32 + k0];
        const float4 f0 = *reinterpret_cast<const float4*>(src);
        const float4 f1 = *reinterpret_cast<const float4*>(src + 4);
        const float ff[8] = {f0.x, f0.y, f0.z, f0.w, f1.x, f1.y, f1.z, f1.w};
        short8 h, l;
        #pragma unroll
        for (int e = 0; e < 8; ++e) {
            const unsigned short hb = f32_to_bf16_rn(ff[e]);
            h[e] = (short)hb;
            l[e] = (short)f32_to_bf16_rn(ff[e] - bf16_bits_to_f32(hb));
        }
        *reinterpret_cast<short8*>(&hi[tb + ci * 8]) = h;
        *reinterpret_cast<short8*>(&lo[tb + ci * 8]) = l;
    }
}

// ====================== plane-fed MFMA GEMM (NT) ===========================
template<int NSPLIT, int ACT, int AMODE, int OUTMODE>
__global__ __launch_bounds__(256) void gemm_pl(
    const short* __restrict__ Ahi, const short* __restrict__ Alo,
    const float* __restrict__ Af32, int AK,
    const short* __restrict__ Bhi, const short* __restrict__ Blo,
    const float* __restrict__ bias,
    float* __restrict__ Cf32, short* __restrict__ Cphi, short* __restrict__ Cplo,
    int N, int KT, int KTout)
{
    __shared__ short lds[NSPLIT * 2 * 4096];

    const int tid  = threadIdx.x;
    const int lane = tid & 63;
    const int w_id = tid >> 6;
    const int wr   = (w_id >> 1) * 64;
    const int wc   = (w_id & 1)  * 64;
    const int m0   = blockIdx.y * 128;
    const int n0   = blockIdx.x * 128;
    const int l15  = lane & 15;
    const int lg   = lane >> 4;

    f32x4 acc[4][4];
    #pragma unroll
    for (int i = 0; i < 4; ++i)
        #pragma unroll
        for (int j = 0; j < 4; ++j) acc[i][j] = (f32x4){0.f, 0.f, 0.f, 0.f};

    for (int kt = 0; kt < KT; ++kt) {
        if (AMODE == 0) {
            const size_t at = ((size_t)blockIdx.y * KT + kt) * 4096;
            #pragma unroll
            for (int q = 0; q < 2; ++q) {
                const int o = (w_id * 2 + q) * 512 + lane * 8;
                glds16(Ahi + at + o, &lds[o]);
                if (NSPLIT > 1) glds16(Alo + at + o, &lds[4096 + o]);
            }
        } else {
            #pragma unroll
            for (int i = 0; i < 2; ++i) {
                const int ci  = tid + i * 256;
                const int row = ci >> 2;
                const int sl  = ci & 3;
                const int k0  = ((sl ^ (row & 3)) << 3);
                const float* src = &Af32[(size_t)(m0 + row) * AK + kt * 32 + k0];
                const float4 f0 = *reinterpret_cast<const float4*>(src);
                const float4 f1 = *reinterpret_cast<const float4*>(src + 4);
                const float ff[8] = {f0.x, f0.y, f0.z, f0.w, f1.x, f1.y, f1.z, f1.w};
                short8 h;
                #pragma unroll
                for (int e = 0; e < 8; ++e) h[e] = (short)f32_to_bf16_rn(ff[e]);
                *reinterpret_cast<short8*>(&lds[ci * 8]) = h;
            }
        }
        {
            const size_t bt = ((size_t)blockIdx.x * KT + kt) * 4096;
            #pragma unroll
            for (int q = 0; q < 2; ++q) {
                const int o = (w_id * 2 + q) * 512 + lane * 8;
                glds16(Bhi + bt + o, &lds[NSPLIT * 4096 + o]);
                if (NSPLIT > 1) glds16(Blo + bt + o, &lds[(NSPLIT + 1) * 4096 + o]);
            }
        }
        __syncthreads();

        bf16x8 bfr[4][NSPLIT];
        #pragma unroll
        for (int fc = 0; fc < 4; ++fc) {
            const int rn  = wc + fc * 16 + l15;
            const int idx = rn * 32 + ((lg ^ (rn & 3)) << 3);
            #pragma unroll
            for (int s = 0; s < NSPLIT; ++s)
                bfr[fc][s] = *reinterpret_cast<const bf16x8*>(&lds[(NSPLIT + s) * 4096 + idx]);
        }
        #pragma unroll
        for (int fr = 0; fr < 4; ++fr) {
            const int rm  = wr + fr * 16 + l15;
            const int idx = rm * 32 + ((lg ^ (rm & 3)) << 3);
            const bf16x8 a0 = *reinterpret_cast<const bf16x8*>(&lds[idx]);
            bf16x8 a1;
            if (NSPLIT > 1)
                a1 = *reinterpret_cast<const bf16x8*>(&lds[4096 + idx]);
            #pragma unroll
            for (int fc = 0; fc < 4; ++fc) {
                acc[fr][fc] = __builtin_amdgcn_mfma_f32_16x16x32_bf16(
                    a0, bfr[fc][0], acc[fr][fc], 0, 0, 0);
                if (NSPLIT > 1) {
                    acc[fr][fc] = __builtin_amdgcn_mfma_f32_16x16x32_bf16(
                        a0, bfr[fc][1], acc[fr][fc], 0, 0, 0);
                    acc[fr][fc] = __builtin_amdgcn_mfma_f32_16x16x32_bf16(
                        a1, bfr[fc][0], acc[fr][fc], 0, 0, 0);
                }
            }
        }
        __syncthreads();
    }

    float bv[4];
    #pragma unroll
    for (int fc = 0; fc < 4; ++fc) {
        const int col = n0 + wc + fc * 16 + l15;
        bv[fc] = (col < N) ? bias[col] : 0.f;
    }
    #pragma unroll
    for (int fr = 0; fr < 4; ++fr) {
        #pragma unroll
        for (int fc = 0; fc < 4; ++fc) {
            const int col = n0 + wc + fc * 16 + l15;
            #pragma unroll
            for (int j = 0; j < 4; ++j) {
                const int rowg = m0 + wr + fr * 16 + lg * 4 + j;
                float v = acc[fr][fc][j] + bv[fc];
                if (ACT == 1) v = fmaxf(v, 0.f);
                else if (ACT == 2) v = 1.f / (1.f + expf(-v));
                if (OUTMODE == 0) {
                    if (col < N) Cf32[(size_t)rowg * N + col] = v;
                } else {
                    const int kto = col >> 5;
                    if (kto < KTout) {
                        const int r = rowg & 127, k = col & 31;
                        const size_t off = ((size_t)blockIdx.y * KTout + kto) * 4096
                                         + r * 32 + (((k >> 3) ^ (r & 3)) << 3) + (k & 7);
                        const unsigned short hb = f32_to_bf16_rn(v);
                        Cphi[off] = (short)hb;
                        if (OUTMODE == 2)
                            Cplo[off] = (short)f32_to_bf16_rn(v - bf16_bits_to_f32(hb));
                    }
                }
            }
        }
    }
}

// ============================ VQ prep (one block) ===========================
__global__ void vq_prep(const float* __restrict__ Wemb, short* __restrict__ planes,
                        double* __restrict__ wn, int* __restrict__ flag_cnt)
{
    const int tid = threadIdx.x;
    if (tid == 0) *flag_cnt = 0;
    if (tid < 128) {
        double s = 0.0;
        for (int k = 0; k < 128; ++k) {
            const double w = (double)Wemb[k * 128 + tid];
            s = fma(w, w, s);
        }
        wn[tid] = s;
    }
    for (int t = tid; t < 16384; t += 256) {
        const int k = t >> 7, n = t & 127;
        const float w = Wemb[t];
        const unsigned short hi = f32_to_bf16_rn(w);
        const unsigned short lo = f32_to_bf16_rn(w - bf16_bits_to_f32(hi));
        const int off = n * 128 + (((k >> 3) ^ (n & 7)) << 3) + (k & 7);
        planes[off]         = (short)hi;
        planes[16384 + off] = (short)lo;
    }
}

// ============================ VQ MFMA + argmin ==============================
// (unchanged — known good)
__global__ __launch_bounds__(512) void vq_mfma(
    const float* __restrict__ z_e, const short* __restrict__ planes,
    const double* __restrict__ wn_g, float* __restrict__ zq,
    int* __restrict__ flag_cnt, int* __restrict__ flag_ids)
{
    __shared__ short  Wsh[32768];
    __shared__ float  zsh[16 * 1024];
    __shared__ double wn_sh[128];
    __shared__ double cmb_v1[128][2];
    __shared__ double cmb_v2[128][2];
    __shared__ int    cmb_i[128][2];
    __shared__ int    idx_sh[128];
    __shared__ int    sflag[16];

    const int tid = threadIdx.x;
    const int b0  = blockIdx.x * 16;

    for (int c = tid; c < 4096; c += 512)
        *reinterpret_cast<int4*>(&Wsh[c * 8]) =
            *reinterpret_cast<const int4*>(&planes[c * 8]);
    for (int c = tid; c < 128; c += 512) wn_sh[c] = wn_g[c];
    for (int c = tid; c < 4096; c += 512) {
        const int D    = c * 16;
        const int s    = D >> 12;
        const int dr   = D & 4095;
        const int srcb = dr ^ (((dr >> 8) & 3) << 5);
        *reinterpret_cast<int4*>(reinterpret_cast<char*>(zsh) + D) =
            *reinterpret_cast<const int4*>(
                reinterpret_cast<const char*>(z_e) + (size_t)(b0 + s) * 4096 + srcb);
    }
    if (tid < 16) sflag[tid] = 0;
    __syncthreads();

    const int lane = tid & 63;
    const int w_id = tid >> 6;
    const int wr   = (w_id >> 1) * 32;
    const int wc   = (w_id & 1) * 64;
    const int l15  = lane & 15;
    const int lg   = lane >> 4;

    f32x4 acc[2][4];
    #pragma unroll
    for (int i = 0; i < 2; ++i)
        #pragma unroll
        for (int j = 0; j < 4; ++j) acc[i][j] = (f32x4){0.f, 0.f, 0.f, 0.f};

    #pragma unroll
    for (int ks = 0; ks < 4; ++ks) {
        bf16x8 bh[4], bl[4];
        #pragma unroll
        for (int cf = 0; cf < 4; ++cf) {
            const int n     = wc + cf * 16 + l15;
            const int slotp = (ks * 4 + lg) ^ (n & 7);
            const int off   = n * 128 + slotp * 8;
            bh[cf] = *reinterpret_cast<const bf16x8*>(&Wsh[off]);
            bl[cf] = *reinterpret_cast<const bf16x8*>(&Wsh[16384 + off]);
        }
        bf16x8 ah[2], al[2];
        #pragma unroll
        for (int rf = 0; rf < 2; ++rf) {
            const int row   = wr + rf * 16 + l15;
            const int s_loc = row >> 3;
            const int d     = row & 7;
            const int kb    = ks * 32 + lg * 8;
            const int xr    = (lg & 3) << 5;
            const char* zb  = reinterpret_cast<const char*>(zsh) + s_loc * 4096;
            bf16x8 h8, L8;
            #pragma unroll
            for (int j = 0; j < 8; ++j) {
                const float a = *reinterpret_cast<const float*>(
                    zb + ((32 * (kb + j) + 4 * d) ^ xr));
                const unsigned short hi = f32_to_bf16_rn(a);
                h8[j] = (short)hi;
                L8[j] = (short)f32_to_bf16_rn(a - bf16_bits_to_f32(hi));
            }
            ah[rf] = h8; al[rf] = L8;
        }
        #pragma unroll
        for (int rf = 0; rf < 2; ++rf)
            #pragma unroll
            for (int cf = 0; cf < 4; ++cf) {
                acc[rf][cf] = __builtin_amdgcn_mfma_f32_16x16x32_bf16(
                    ah[rf], bh[cf], acc[rf][cf], 0, 0, 0);
                acc[rf][cf] = __builtin_amdgcn_mfma_f32_16x16x32_bf16(
                    ah[rf], bl[cf], acc[rf][cf], 0, 0, 0);
                acc[rf][cf] = __builtin_amdgcn_mfma_f32_16x16x32_bf16(
                    al[rf], bh[cf], acc[rf][cf], 0, 0, 0);
            }
    }

    #pragma unroll
    for (int rf = 0; rf < 2; ++rf)
        #pragma unroll
        for (int j = 0; j < 4; ++j) {
            double v1 = 1e300, v2 = 1e300; int i1 = 0;
            #pragma unroll
            for (int cf = 0; cf < 4; ++cf) {
                const int n = wc + cf * 16 + l15;
                const double v = wn_sh[n] - 2.0 * (double)acc[rf][cf][j];
                if (v < v1)      { v2 = v1; v1 = v; i1 = n; }
                else if (v < v2) { v2 = v; }
            }
            #pragma unroll
            for (int off = 1; off < 16; off <<= 1) {
                const double ov1 = __shfl_xor(v1, off);
                const int    oi1 = __shfl_xor(i1, off);
                const double ov2 = __shfl_xor(v2, off);
                if (ov1 < v1 || (ov1 == v1 && oi1 < i1)) {
                    v2 = fmin(v1, ov2); v1 = ov1; i1 = oi1;
                } else {
                    v2 = fmin(v2, ov1);
                }
            }
            if (l15 == 0) {
                const int r = wr + rf * 16 + lg * 4 + j;
                cmb_v1[r][w_id & 1] = v1;
                cmb_v2[r][w_id & 1] = v2;
                cmb_i [r][w_id & 1] = i1;
            }
        }
    __syncthreads();

    if (tid < 128) {
        const double v1a = cmb_v1[tid][0], v1b = cmb_v1[tid][1];
        double v1, v2; int i1;
        if (v1b < v1a) { v1 = v1b; i1 = cmb_i[tid][1]; v2 = fmin(v1a, cmb_v2[tid][1]); }
        else           { v1 = v1a; i1 = cmb_i[tid][0]; v2 = fmin(v1b, cmb_v2[tid][0]); }
        idx_sh[tid] = i1;
        if (v2 - v1 < GAP_T) sflag[tid >> 3] = 1;
    }
    __syncthreads();
    if (tid < 16 && sflag[tid]) {
        const int p = atomicAdd(flag_cnt, 1);
        flag_ids[p] = b0 + tid;
    }

    for (int t = tid; t < 16384; t += 512) {
        const int s = t >> 10, i = t & 1023;
        const int k = i >> 3, d = i & 7;
        const int n = idx_sh[(s << 3) | d];
        const int off = n * 128 + (((k >> 3) ^ (n & 7)) << 3) + (k & 7);
        const float val = bf16_bits_to_f32((unsigned short)Wsh[off]) +
                          bf16_bits_to_f32((unsigned short)Wsh[16384 + off]);
        zq[(size_t)(b0 + s) * 1024 + i] = val;
    }
}

// =============== exact f64 fixup, round 7: wave-split-k, 8 samples ==========
// LDS (bytes, phase-aliased, 157120 total):
//   h1sh  f64[8][402]   @ 0        (whole kernel)        25728
//   xsh   f32[8][3072]  @ 25728    (phase 1 only)        98304 -> ends 124032
//   wesh  f32[16384]    @ 25728    (phase 2+, alias x)   65536 -> ends 91264
//   zsh   f64[8][1025]  @ 91264    (phase 2+)            65600 -> ends 156864
//   idxf  int[64]       @ 156864                           256 -> ends 157120
__global__ __launch_bounds__(512) void vq_fixup(
    const float* __restrict__ x,  const float* __restrict__ W1,
    const float* __restrict__ b1, const float* __restrict__ W2,
    const float* __restrict__ b2, const float* __restrict__ Wemb,
    const int* __restrict__ flag_cnt, const int* __restrict__ flag_ids,
    float* __restrict__ zq_out)
{
    __shared__ float4 smem_v[9820];
    char*   smem = reinterpret_cast<char*>(smem_v);
    double* h1sh = reinterpret_cast<double*>(smem);            // stride 402
    float*  xsh  = reinterpret_cast<float*>(smem + 25728);
    float*  wesh = reinterpret_cast<float*>(smem + 25728);
    double* zsh  = reinterpret_cast<double*>(smem + 91264);    // stride 1025
    int*    idxf = reinterpret_cast<int*>(smem + 156864);

    const int tid  = threadIdx.x;
    const int lane = tid & 63;
    const int w_id = tid >> 6;          // 0..7
    const int cnt  = *flag_cnt;

    for (int base = blockIdx.x * 8; base < cnt; base += gridDim.x * 8) {
        const int ns = min(8, cnt - base);
        __syncthreads();   // previous iteration fully done (xsh aliases wesh)

        // ---- phase 1a: stage 8 x-rows (f32), zero-fill inactive ----
        for (int i = tid; i < 8 * 768; i += 512) {
            const int s = i / 768, k4 = i - s * 768;
            float4 v = make_float4(0.f, 0.f, 0.f, 0.f);
            if (s < ns)
                v = reinterpret_cast<const float4*>(
                        &x[(size_t)flag_ids[base + s] * 3072])[k4];
            reinterpret_cast<float4*>(xsh)[i] = v;
        }
        __syncthreads();

        // ---- phase 1b: h1 = relu(x@W1^T+b1), wave-per-j, 64-lane k-split ----
        for (int j = w_id; j < 400; j += 8) {
            double acc[8];
            #pragma unroll
            for (int s = 0; s < 8; ++s) acc[s] = 0.0;
            const float* wrow = &W1[(size_t)j * 3072];
            #pragma unroll 4
            for (int c = 0; c < 12; ++c) {
                const float4 w4 = *reinterpret_cast<const float4*>(
                    &wrow[c * 256 + lane * 4]);
                #pragma unroll
                for (int s = 0; s < 8; ++s) {
                    const float4 x4 = *reinterpret_cast<const float4*>(
                        &xsh[s * 3072 + c * 256 + lane * 4]);
                    acc[s] = fma((double)w4.x, (double)x4.x, acc[s]);
                    acc[s] = fma((double)w4.y, (double)x4.y, acc[s]);
                    acc[s] = fma((double)w4.z, (double)x4.z, acc[s]);
                    acc[s] = fma((double)w4.w, (double)x4.w, acc[s]);
                }
            }
            #pragma unroll
            for (int off = 32; off > 0; off >>= 1)
                #pragma unroll
                for (int s = 0; s < 8; ++s)
                    acc[s] += __shfl_xor(acc[s], off);
            const double bj = (double)b1[j];
            #pragma unroll
            for (int s = 0; s < 8; ++s)
                if (lane == s) {
                    const double v = acc[s] + bj;
                    h1sh[s * 402 + j] = v > 0.0 ? v : 0.0;
                }
        }
        __syncthreads();   // xsh dead from here

        // ---- phase 2: stage Wemb (aliases xsh) + z = h1@W2^T+b2 (f64) ----
        for (int i = tid; i < 4096; i += 512)
            reinterpret_cast<float4*>(wesh)[i] =
                reinterpret_cast<const float4*>(Wemb)[i];
        {
            const int s   = tid & 7;
            const int zig = tid >> 3;            // 0..63
            for (int pass = 0; pass < 16; ++pass) {
                const int zi = pass * 64 + zig;
                double acc = (double)b2[zi];
                const float4* wr = reinterpret_cast<const float4*>(
                    &W2[(size_t)zi * 400]);
                const double* hp = &h1sh[s * 402];
                #pragma unroll 4
                for (int k4 = 0; k4 < 100; ++k4) {
                    const float4 w = wr[k4];
                    acc = fma((double)w.x, hp[k4 * 4 + 0], acc);
                    acc = fma((double)w.y, hp[k4 * 4 + 1], acc);
                    acc = fma((double)w.z, hp[k4 * 4 + 2], acc);
                    acc = fma((double)w.w, hp[k4 * 4 + 3], acc);
                }
                zsh[s * 1025 + zi] = acc;
            }
        }
        __syncthreads();

        // ---- phase 3: exact distances + argmin; wave w = sample w ----
        {
            const int s = w_id;
            #pragma unroll
            for (int d = 0; d < 8; ++d) {
                double d1 = 0.0, d2 = 0.0;
                const double* zp = &zsh[s * 1025 + d];
                for (int k = 0; k < 128; ++k) {
                    const double zv = zp[k * 8];
                    const double wA = (double)wesh[k * 128 + lane];
                    const double wB = (double)wesh[k * 128 + 64 + lane];
                    const double t1 = zv - wA;
                    const double t2 = zv - wB;
                    d1 = fma(t1, t1, d1);
                    d2 = fma(t2, t2, d2);
                }
                double v; int ix;
                if (d2 < d1) { v = d2; ix = lane + 64; }
                else         { v = d1; ix = lane; }
                #pragma unroll
                for (int off = 32; off > 0; off >>= 1) {
                    const double ov = __shfl_down(v, off);
                    const int    oi = __shfl_down(ix, off);
                    if (ov < v || (ov == v && oi < ix)) { v = ov; ix = oi; }
                }
                if (lane == 0) idxf[s * 8 + d] = ix;
            }
        }
        __syncthreads();

        // ---- phase 4: rewrite z_q rows for flagged samples ----
        for (int i = tid; i < ns * 1024; i += 512) {
            const int s = i >> 10, ii = i & 1023;
            const int k = ii >> 3, d = ii & 7;
            zq_out[(size_t)flag_ids[base + s] * 1024 + ii] =
                wesh[k * 128 + idxf[s * 8 + d]];
        }
    }
}

// ---------------------------------------------------------------------------
extern "C" void kernel_launch(void* const* d_in, const int* in_sizes, int n_in,
                              void* d_out, int out_size, void* d_ws, size_t ws_size,
                              hipStream_t stream)
{
    const float* x    = (const float*)d_in[0];
    const float* W1   = (const float*)d_in[1];
    const float* b1   = (const float*)d_in[2];
    const float* W2   = (const float*)d_in[3];
    const float* b2   = (const float*)d_in[4];
    const float* W3   = (const float*)d_in[5];
    const float* b3   = (const float*)d_in[6];
    const float* W4   = (const float*)d_in[7];
    const float* b4   = (const float*)d_in[8];
    const float* Wemb = (const float*)d_in[9];

    const int B = 16384;
    float* out   = (float*)d_out;
    float* recon = out;                                // B*3072
    float* z_e   = out + (size_t)B * 3072;             // B*1024
    float* emb_o = z_e + (size_t)B * 1024;             // B*1024 == z_q

    constexpr size_t X_PL  = 50331648;
    constexpr size_t H1_PL = 6815744;
    constexpr size_t H3_PL = 6815744;
    constexpr size_t W1_PL = 1572864;
    constexpr size_t W2_PL = 425984;
    constexpr size_t W3_PL = 524288;
    constexpr size_t W4_PL = 1277952;

    short* xh  = (short*)recon;
    short* xl  = xh + X_PL;
    short* h1h = (short*)emb_o;
    short* h1l = h1h + H1_PL;

    short*  h3h      = (short*)d_ws;
    short*  w1h      = h3h + H3_PL;
    short*  w1l      = w1h + W1_PL;
    short*  w2h      = w1l + W1_PL;
    short*  w2l      = w2h + W2_PL;
    short*  w3h      = w2l + W2_PL;
    short*  w4h      = w3h + W3_PL;
    short*  wembpl   = w4h + W4_PL;
    double* wn       = (double*)(wembpl + 32768);
    int*    flag_cnt = (int*)(wn + 128);
    int*    flag_ids = flag_cnt + 64;

    prep_wplanes<<<dim3(384), dim3(256), 0, stream>>>(W1, 400, 3072, 96, w1h, w1l);
    prep_wplanes<<<dim3(104), dim3(256), 0, stream>>>(W2, 1024, 400, 13, w2h, w2l);
    prep_wplanes<<<dim3(128), dim3(256), 0, stream>>>(W3, 400, 1024, 32, w3h, nullptr);
    prep_wplanes<<<dim3(312), dim3(256), 0, stream>>>(W4, 3072, 400, 13, w4h, nullptr);
    prep_xplanes<<<dim3(12288), dim3(256), 0, stream>>>(x, xh, xl);
    vq_prep<<<dim3(1), dim3(256), 0, stream>>>(Wemb, wembpl, wn, flag_cnt);

    gemm_pl<2, 1, 0, 2><<<dim3(4, 128), dim3(256), 0, stream>>>(
        xh, xl, nullptr, 0, w1h, w1l, b1, nullptr, h1h, h1l, 400, 96, 13);
    gemm_pl<2, 0, 0, 0><<<dim3(8, 128), dim3(256), 0, stream>>>(
        h1h, h1l, nullptr, 0, w2h, w2l, b2, z_e, nullptr, nullptr, 1024, 13, 0);

    vq_mfma<<<dim3(1024), dim3(512), 0, stream>>>(z_e, wembpl, wn, emb_o,
                                                  flag_cnt, flag_ids);
    vq_fixup<<<dim3(256), dim3(512), 0, stream>>>(x, W1, b1, W2, b2, Wemb,
                                                  flag_cnt, flag_ids, emb_o);

    gemm_pl<1, 1, 1, 1><<<dim3(4, 128), dim3(256), 0, stream>>>(
        nullptr, nullptr, emb_o, 1024, w3h, nullptr, b3, nullptr, h3h, nullptr,
        400, 32, 13);
    gemm_pl<1, 2, 0, 0><<<dim3(24, 128), dim3(256), 0, stream>>>(
        h3h, nullptr, nullptr, 0, w4h, nullptr, b4, recon, nullptr, nullptr,
        3072, 13, 0);
}

// Round 8
// 777.392 us; speedup vs baseline: 1.7886x; 1.7886x over previous
//
#include <hip/hip_runtime.h>
#include <math.h>

// ---------------------------------------------------------------------------
// VQ-VAE forward on MI355X — round 8: fixup as tiled f64 GEMM pipeline.
//   g1: h1 = relu(x @ W1^T + b1)        [x,W1 hi/lo planes -> h1 hi/lo planes]
//   g2: z_e = h1 @ W2^T + b2            [planes -> f32 z_e output]
//   vq_mfma: MFMA dots + top-2 argmin + gap flag (GAP_T=2e-4)
//   fixup:  F1  Part[c] = gatherX @ W1^T   (64^2-tile f64 GEMM, 6-way split-K)
//           FR  H1f = relu(sum Part + b1)
//           F2  Zf  = H1f @ W2^T + b2     (64^2-tile f64 GEMM)
//           F3  exact distances + argmin + z_q scatter
//   g3: h3 = relu(z_q @ W3^T + b3);  g4: recon = sigmoid(h3 @ W4^T + b4)
// Fixup scratch lives in the recon output section (x-planes there are dead
// after g1; g4 overwrites recon at the end): Part@+0, H1f@+80MB, Zf@+96MB.
// Round-6/7 fixups re-streamed W1/W2 per small sample group (311/790us,
// latency-bound); tiled GEMMs amortize weights across 64-row tiles.
// ---------------------------------------------------------------------------

typedef short bf16x8 __attribute__((ext_vector_type(8)));
typedef short short8 __attribute__((ext_vector_type(8)));
typedef float f32x4  __attribute__((ext_vector_type(4)));

#define GAP_T   2e-4
#define FIX_CAP 4096

__device__ __forceinline__ unsigned short f32_to_bf16_rn(float v) {
    union { float f; unsigned u; } c; c.f = v;
    unsigned r = c.u + 0x7FFFu + ((c.u >> 16) & 1u);
    return (unsigned short)(r >> 16);
}
__device__ __forceinline__ float bf16_bits_to_f32(unsigned short b) {
    union { unsigned u; float f; } c; c.u = ((unsigned)b) << 16;
    return c.f;
}
__device__ __forceinline__ void glds16(const short* g, short* l) {
    __builtin_amdgcn_global_load_lds(
        (const __attribute__((address_space(1))) unsigned int*)g,
        (__attribute__((address_space(3))) unsigned int*)l, 16, 0, 0);
}

// ===================== plane prep: weights (B operand) ======================
__global__ __launch_bounds__(256) void prep_wplanes(
    const float* __restrict__ Wsrc, int N, int K, int KT,
    short* __restrict__ hi, short* __restrict__ lo)
{
    const int kt = blockIdx.x % KT;
    const int nb = blockIdx.x / KT;
    const size_t tb = (size_t)blockIdx.x * 4096;
    for (int ci = threadIdx.x; ci < 512; ci += 256) {
        const int row = ci >> 2;
        const int sl  = ci & 3;
        const int k0  = ((sl ^ (row & 3)) << 3);
        const int n   = nb * 128 + row;
        const int kk  = kt * 32 + k0;
        float f[8];
        #pragma unroll
        for (int e = 0; e < 8; ++e)
            f[e] = (n < N && kk + e < K) ? Wsrc[(size_t)n * K + kk + e] : 0.f;
        short8 h, l;
        #pragma unroll
        for (int e = 0; e < 8; ++e) {
            const unsigned short hb = f32_to_bf16_rn(f[e]);
            h[e] = (short)hb;
            l[e] = (short)f32_to_bf16_rn(f[e] - bf16_bits_to_f32(hb));
        }
        *reinterpret_cast<short8*>(&hi[tb + ci * 8]) = h;
        if (lo) *reinterpret_cast<short8*>(&lo[tb + ci * 8]) = l;
    }
}

// ========================= plane prep: x (A operand) ========================
__global__ __launch_bounds__(256) void prep_xplanes(
    const float* __restrict__ x, short* __restrict__ hi, short* __restrict__ lo)
{
    const int kt = blockIdx.x % 96;
    const int mb = blockIdx.x / 96;
    const size_t tb = (size_t)blockIdx.x * 4096;
    for (int ci = threadIdx.x; ci < 512; ci += 256) {
        const int row = ci >> 2;
        const int sl  = ci & 3;
        const int k0  = ((sl ^ (row & 3)) << 3);
        const float* src = &x[(size_t)(mb * 128 + row) * 3072 + kt * 32 + k0];
        const float4 f0 = *reinterpret_cast<const float4*>(src);
        const float4 f1 = *reinterpret_cast<const float4*>(src + 4);
        const float ff[8] = {f0.x, f0.y, f0.z, f0.w, f1.x, f1.y, f1.z, f1.w};
        short8 h, l;
        #pragma unroll
        for (int e = 0; e < 8; ++e) {
            const unsigned short hb = f32_to_bf16_rn(ff[e]);
            h[e] = (short)hb;
            l[e] = (short)f32_to_bf16_rn(ff[e] - bf16_bits_to_f32(hb));
        }
        *reinterpret_cast<short8*>(&hi[tb + ci * 8]) = h;
        *reinterpret_cast<short8*>(&lo[tb + ci * 8]) = l;
    }
}

// ====================== plane-fed MFMA GEMM (NT) ===========================
template<int NSPLIT, int ACT, int AMODE, int OUTMODE>
__global__ __launch_bounds__(256) void gemm_pl(
    const short* __restrict__ Ahi, const short* __restrict__ Alo,
    const float* __restrict__ Af32, int AK,
    const short* __restrict__ Bhi, const short* __restrict__ Blo,
    const float* __restrict__ bias,
    float* __restrict__ Cf32, short* __restrict__ Cphi, short* __restrict__ Cplo,
    int N, int KT, int KTout)
{
    __shared__ short lds[NSPLIT * 2 * 4096];

    const int tid  = threadIdx.x;
    const int lane = tid & 63;
    const int w_id = tid >> 6;
    const int wr   = (w_id >> 1) * 64;
    const int wc   = (w_id & 1)  * 64;
    const int m0   = blockIdx.y * 128;
    const int n0   = blockIdx.x * 128;
    const int l15  = lane & 15;
    const int lg   = lane >> 4;

    f32x4 acc[4][4];
    #pragma unroll
    for (int i = 0; i < 4; ++i)
        #pragma unroll
        for (int j = 0; j < 4; ++j) acc[i][j] = (f32x4){0.f, 0.f, 0.f, 0.f};

    for (int kt = 0; kt < KT; ++kt) {
        if (AMODE == 0) {
            const size_t at = ((size_t)blockIdx.y * KT + kt) * 4096;
            #pragma unroll
            for (int q = 0; q < 2; ++q) {
                const int o = (w_id * 2 + q) * 512 + lane * 8;
                glds16(Ahi + at + o, &lds[o]);
                if (NSPLIT > 1) glds16(Alo + at + o, &lds[4096 + o]);
            }
        } else {
            #pragma unroll
            for (int i = 0; i < 2; ++i) {
                const int ci  = tid + i * 256;
                const int row = ci >> 2;
                const int sl  = ci & 3;
                const int k0  = ((sl ^ (row & 3)) << 3);
                const float* src = &Af32[(size_t)(m0 + row) * AK + kt * 32 + k0];
                const float4 f0 = *reinterpret_cast<const float4*>(src);
                const float4 f1 = *reinterpret_cast<const float4*>(src + 4);
                const float ff[8] = {f0.x, f0.y, f0.z, f0.w, f1.x, f1.y, f1.z, f1.w};
                short8 h;
                #pragma unroll
                for (int e = 0; e < 8; ++e) h[e] = (short)f32_to_bf16_rn(ff[e]);
                *reinterpret_cast<short8*>(&lds[ci * 8]) = h;
            }
        }
        {
            const size_t bt = ((size_t)blockIdx.x * KT + kt) * 4096;
            #pragma unroll
            for (int q = 0; q < 2; ++q) {
                const int o = (w_id * 2 + q) * 512 + lane * 8;
                glds16(Bhi + bt + o, &lds[NSPLIT * 4096 + o]);
                if (NSPLIT > 1) glds16(Blo + bt + o, &lds[(NSPLIT + 1) * 4096 + o]);
            }
        }
        __syncthreads();

        bf16x8 bfr[4][NSPLIT];
        #pragma unroll
        for (int fc = 0; fc < 4; ++fc) {
            const int rn  = wc + fc * 16 + l15;
            const int idx = rn * 32 + ((lg ^ (rn & 3)) << 3);
            #pragma unroll
            for (int s = 0; s < NSPLIT; ++s)
                bfr[fc][s] = *reinterpret_cast<const bf16x8*>(&lds[(NSPLIT + s) * 4096 + idx]);
        }
        #pragma unroll
        for (int fr = 0; fr < 4; ++fr) {
            const int rm  = wr + fr * 16 + l15;
            const int idx = rm * 32 + ((lg ^ (rm & 3)) << 3);
            const bf16x8 a0 = *reinterpret_cast<const bf16x8*>(&lds[idx]);
            bf16x8 a1;
            if (NSPLIT > 1)
                a1 = *reinterpret_cast<const bf16x8*>(&lds[4096 + idx]);
            #pragma unroll
            for (int fc = 0; fc < 4; ++fc) {
                acc[fr][fc] = __builtin_amdgcn_mfma_f32_16x16x32_bf16(
                    a0, bfr[fc][0], acc[fr][fc], 0, 0, 0);
                if (NSPLIT > 1) {
                    acc[fr][fc] = __builtin_amdgcn_mfma_f32_16x16x32_bf16(
                        a0, bfr[fc][1], acc[fr][fc], 0, 0, 0);
                    acc[fr][fc] = __builtin_amdgcn_mfma_f32_16x16x32_bf16(
                        a1, bfr[fc][0], acc[fr][fc], 0, 0, 0);
                }
            }
        }
        __syncthreads();
    }

    float bv[4];
    #pragma unroll
    for (int fc = 0; fc < 4; ++fc) {
        const int col = n0 + wc + fc * 16 + l15;
        bv[fc] = (col < N) ? bias[col] : 0.f;
    }
    #pragma unroll
    for (int fr = 0; fr < 4; ++fr) {
        #pragma unroll
        for (int fc = 0; fc < 4; ++fc) {
            const int col = n0 + wc + fc * 16 + l15;
            #pragma unroll
            for (int j = 0; j < 4; ++j) {
                const int rowg = m0 + wr + fr * 16 + lg * 4 + j;
                float v = acc[fr][fc][j] + bv[fc];
                if (ACT == 1) v = fmaxf(v, 0.f);
                else if (ACT == 2) v = 1.f / (1.f + expf(-v));
                if (OUTMODE == 0) {
                    if (col < N) Cf32[(size_t)rowg * N + col] = v;
                } else {
                    const int kto = col >> 5;
                    if (kto < KTout) {
                        const int r = rowg & 127, k = col & 31;
                        const size_t off = ((size_t)blockIdx.y * KTout + kto) * 4096
                                         + r * 32 + (((k >> 3) ^ (r & 3)) << 3) + (k & 7);
                        const unsigned short hb = f32_to_bf16_rn(v);
                        Cphi[off] = (short)hb;
                        if (OUTMODE == 2)
                            Cplo[off] = (short)f32_to_bf16_rn(v - bf16_bits_to_f32(hb));
                    }
                }
            }
        }
    }
}

// ============================ VQ prep (one block) ===========================
__global__ void vq_prep(const float* __restrict__ Wemb, short* __restrict__ planes,
                        double* __restrict__ wn, int* __restrict__ flag_cnt)
{
    const int tid = threadIdx.x;
    if (tid == 0) *flag_cnt = 0;
    if (tid < 128) {
        double s = 0.0;
        for (int k = 0; k < 128; ++k) {
            const double w = (double)Wemb[k * 128 + tid];
            s = fma(w, w, s);
        }
        wn[tid] = s;
    }
    for (int t = tid; t < 16384; t += 256) {
        const int k = t >> 7, n = t & 127;
        const float w = Wemb[t];
        const unsigned short hi = f32_to_bf16_rn(w);
        const unsigned short lo = f32_to_bf16_rn(w - bf16_bits_to_f32(hi));
        const int off = n * 128 + (((k >> 3) ^ (n & 7)) << 3) + (k & 7);
        planes[off]         = (short)hi;
        planes[16384 + off] = (short)lo;
    }
}

// ============================ VQ MFMA + argmin ==============================
// (unchanged — known good)
__global__ __launch_bounds__(512) void vq_mfma(
    const float* __restrict__ z_e, const short* __restrict__ planes,
    const double* __restrict__ wn_g, float* __restrict__ zq,
    int* __restrict__ flag_cnt, int* __restrict__ flag_ids)
{
    __shared__ short  Wsh[32768];
    __shared__ float  zsh[16 * 1024];
    __shared__ double wn_sh[128];
    __shared__ double cmb_v1[128][2];
    __shared__ double cmb_v2[128][2];
    __shared__ int    cmb_i[128][2];
    __shared__ int    idx_sh[128];
    __shared__ int    sflag[16];

    const int tid = threadIdx.x;
    const int b0  = blockIdx.x * 16;

    for (int c = tid; c < 4096; c += 512)
        *reinterpret_cast<int4*>(&Wsh[c * 8]) =
            *reinterpret_cast<const int4*>(&planes[c * 8]);
    for (int c = tid; c < 128; c += 512) wn_sh[c] = wn_g[c];
    for (int c = tid; c < 4096; c += 512) {
        const int D    = c * 16;
        const int s    = D >> 12;
        const int dr   = D & 4095;
        const int srcb = dr ^ (((dr >> 8) & 3) << 5);
        *reinterpret_cast<int4*>(reinterpret_cast<char*>(zsh) + D) =
            *reinterpret_cast<const int4*>(
                reinterpret_cast<const char*>(z_e) + (size_t)(b0 + s) * 4096 + srcb);
    }
    if (tid < 16) sflag[tid] = 0;
    __syncthreads();

    const int lane = tid & 63;
    const int w_id = tid >> 6;
    const int wr   = (w_id >> 1) * 32;
    const int wc   = (w_id & 1) * 64;
    const int l15  = lane & 15;
    const int lg   = lane >> 4;

    f32x4 acc[2][4];
    #pragma unroll
    for (int i = 0; i < 2; ++i)
        #pragma unroll
        for (int j = 0; j < 4; ++j) acc[i][j] = (f32x4){0.f, 0.f, 0.f, 0.f};

    #pragma unroll
    for (int ks = 0; ks < 4; ++ks) {
        bf16x8 bh[4], bl[4];
        #pragma unroll
        for (int cf = 0; cf < 4; ++cf) {
            const int n     = wc + cf * 16 + l15;
            const int slotp = (ks * 4 + lg) ^ (n & 7);
            const int off   = n * 128 + slotp * 8;
            bh[cf] = *reinterpret_cast<const bf16x8*>(&Wsh[off]);
            bl[cf] = *reinterpret_cast<const bf16x8*>(&Wsh[16384 + off]);
        }
        bf16x8 ah[2], al[2];
        #pragma unroll
        for (int rf = 0; rf < 2; ++rf) {
            const int row   = wr + rf * 16 + l15;
            const int s_loc = row >> 3;
            const int d     = row & 7;
            const int kb    = ks * 32 + lg * 8;
            const int xr    = (lg & 3) << 5;
            const char* zb  = reinterpret_cast<const char*>(zsh) + s_loc * 4096;
            bf16x8 h8, L8;
            #pragma unroll
            for (int j = 0; j < 8; ++j) {
                const float a = *reinterpret_cast<const float*>(
                    zb + ((32 * (kb + j) + 4 * d) ^ xr));
                const unsigned short hi = f32_to_bf16_rn(a);
                h8[j] = (short)hi;
                L8[j] = (short)f32_to_bf16_rn(a - bf16_bits_to_f32(hi));
            }
            ah[rf] = h8; al[rf] = L8;
        }
        #pragma unroll
        for (int rf = 0; rf < 2; ++rf)
            #pragma unroll
            for (int cf = 0; cf < 4; ++cf) {
                acc[rf][cf] = __builtin_amdgcn_mfma_f32_16x16x32_bf16(
                    ah[rf], bh[cf], acc[rf][cf], 0, 0, 0);
                acc[rf][cf] = __builtin_amdgcn_mfma_f32_16x16x32_bf16(
                    ah[rf], bl[cf], acc[rf][cf], 0, 0, 0);
                acc[rf][cf] = __builtin_amdgcn_mfma_f32_16x16x32_bf16(
                    al[rf], bh[cf], acc[rf][cf], 0, 0, 0);
            }
    }

    #pragma unroll
    for (int rf = 0; rf < 2; ++rf)
        #pragma unroll
        for (int j = 0; j < 4; ++j) {
            double v1 = 1e300, v2 = 1e300; int i1 = 0;
            #pragma unroll
            for (int cf = 0; cf < 4; ++cf) {
                const int n = wc + cf * 16 + l15;
                const double v = wn_sh[n] - 2.0 * (double)acc[rf][cf][j];
                if (v < v1)      { v2 = v1; v1 = v; i1 = n; }
                else if (v < v2) { v2 = v; }
            }
            #pragma unroll
            for (int off = 1; off < 16; off <<= 1) {
                const double ov1 = __shfl_xor(v1, off);
                const int    oi1 = __shfl_xor(i1, off);
                const double ov2 = __shfl_xor(v2, off);
                if (ov1 < v1 || (ov1 == v1 && oi1 < i1)) {
                    v2 = fmin(v1, ov2); v1 = ov1; i1 = oi1;
                } else {
                    v2 = fmin(v2, ov1);
                }
            }
            if (l15 == 0) {
                const int r = wr + rf * 16 + lg * 4 + j;
                cmb_v1[r][w_id & 1] = v1;
                cmb_v2[r][w_id & 1] = v2;
                cmb_i [r][w_id & 1] = i1;
            }
        }
    __syncthreads();

    if (tid < 128) {
        const double v1a = cmb_v1[tid][0], v1b = cmb_v1[tid][1];
        double v1, v2; int i1;
        if (v1b < v1a) { v1 = v1b; i1 = cmb_i[tid][1]; v2 = fmin(v1a, cmb_v2[tid][1]); }
        else           { v1 = v1a; i1 = cmb_i[tid][0]; v2 = fmin(v1b, cmb_v2[tid][0]); }
        idx_sh[tid] = i1;
        if (v2 - v1 < GAP_T) sflag[tid >> 3] = 1;
    }
    __syncthreads();
    if (tid < 16 && sflag[tid]) {
        const int p = atomicAdd(flag_cnt, 1);
        flag_ids[p] = b0 + tid;
    }

    for (int t = tid; t < 16384; t += 512) {
        const int s = t >> 10, i = t & 1023;
        const int k = i >> 3, d = i & 7;
        const int n = idx_sh[(s << 3) | d];
        const int off = n * 128 + (((k >> 3) ^ (n & 7)) << 3) + (k & 7);
        const float val = bf16_bits_to_f32((unsigned short)Wsh[off]) +
                          bf16_bits_to_f32((unsigned short)Wsh[16384 + off]);
        zq[(size_t)(b0 + s) * 1024 + i] = val;
    }
}

// ================= fixup F1/F2: 64x64-tile f64 GEMM (NT) ===================
// C[m,n] (f64) = A[m,:K] . W[n,:K]  (+ bias). A rows gathered via ids when
// GATHER. SPLITK: blockIdx.z selects K-chunk of klen; C offset by chunk.
#define FLP 68
template<bool GATHER, bool SPLITK, typename TA>
__global__ __launch_bounds__(256) void gemm_f64t(
    const TA* __restrict__ A, const float* __restrict__ Wf,
    const int* __restrict__ ids, const int* __restrict__ cntp,
    const float* __restrict__ bias, double* __restrict__ C,
    int AK, int N, int CN, int klen, int cap)
{
    __shared__ double As[16 * FLP];
    __shared__ double Ws[16 * FLP];

    const int tid = threadIdx.x;
    const int tx  = tid & 15;
    const int ty  = tid >> 4;
    const int m0  = blockIdx.y * 64;
    const int n0  = blockIdx.x * 64;
    const int cnt = (*cntp < cap) ? *cntp : cap;
    if (m0 >= cnt) return;

    const int k0 = SPLITK ? blockIdx.z * klen : 0;
    if (SPLITK) C += (size_t)blockIdx.z * cap * CN;

    const int srow = tid >> 2;          // 0..63
    const int sc4  = (tid & 3) << 2;    // 0,4,8,12

    const TA* arow;
    if (GATHER) {
        const int m  = m0 + srow;
        const int id = (m < cnt) ? ids[m] : 0;
        arow = A + (size_t)id * AK;
    } else {
        arow = A + (size_t)(m0 + srow) * AK;
    }
    const int   nrow = n0 + srow;
    const float* wrow = Wf + (size_t)(nrow < N ? nrow : 0) * AK;
    const bool  wok  = (nrow < N);

    double acc[4][4];
    #pragma unroll
    for (int i = 0; i < 4; ++i)
        #pragma unroll
        for (int j = 0; j < 4; ++j) acc[i][j] = 0.0;

    for (int kt = 0; kt < klen; kt += 16) {
        const int kb = k0 + kt + sc4;
        // stage A (f32->f64 or f64 direct)
        if constexpr (sizeof(TA) == 4) {
            const float4 v = *reinterpret_cast<const float4*>(&arow[kb]);
            As[(sc4 + 0) * FLP + srow] = (double)v.x;
            As[(sc4 + 1) * FLP + srow] = (double)v.y;
            As[(sc4 + 2) * FLP + srow] = (double)v.z;
            As[(sc4 + 3) * FLP + srow] = (double)v.w;
        } else {
            const double2 v0 = *reinterpret_cast<const double2*>(&arow[kb]);
            const double2 v1 = *reinterpret_cast<const double2*>(&arow[kb + 2]);
            As[(sc4 + 0) * FLP + srow] = v0.x;
            As[(sc4 + 1) * FLP + srow] = v0.y;
            As[(sc4 + 2) * FLP + srow] = v1.x;
            As[(sc4 + 3) * FLP + srow] = v1.y;
        }
        // stage W
        float4 w = make_float4(0.f, 0.f, 0.f, 0.f);
        if (wok) w = *reinterpret_cast<const float4*>(&wrow[kb]);
        Ws[(sc4 + 0) * FLP + srow] = (double)w.x;
        Ws[(sc4 + 1) * FLP + srow] = (double)w.y;
        Ws[(sc4 + 2) * FLP + srow] = (double)w.z;
        Ws[(sc4 + 3) * FLP + srow] = (double)w.w;
        __syncthreads();

        #pragma unroll
        for (int k = 0; k < 16; ++k) {
            const double2 A0 = *reinterpret_cast<const double2*>(&As[k * FLP + ty * 4]);
            const double2 A1 = *reinterpret_cast<const double2*>(&As[k * FLP + ty * 4 + 2]);
            const double2 B0 = *reinterpret_cast<const double2*>(&Ws[k * FLP + tx * 4]);
            const double2 B1 = *reinterpret_cast<const double2*>(&Ws[k * FLP + tx * 4 + 2]);
            const double a[4] = {A0.x, A0.y, A1.x, A1.y};
            const double b[4] = {B0.x, B0.y, B1.x, B1.y};
            #pragma unroll
            for (int i = 0; i < 4; ++i)
                #pragma unroll
                for (int j = 0; j < 4; ++j)
                    acc[i][j] = fma(a[i], b[j], acc[i][j]);
        }
        __syncthreads();
    }

    #pragma unroll
    for (int i = 0; i < 4; ++i) {
        const int row = m0 + ty * 4 + i;
        #pragma unroll
        for (int j = 0; j < 4; ++j) {
            const int col = n0 + tx * 4 + j;
            if (col < N)
                C[(size_t)row * CN + col] =
                    acc[i][j] + (bias ? (double)bias[col] : 0.0);
        }
    }
}

// ============ fixup FR: H1f = relu(sum_c Part[c] + b1) ======================
__global__ __launch_bounds__(256) void fix_reduce(
    const double* __restrict__ Part, const float* __restrict__ b1,
    const int* __restrict__ cntp, double* __restrict__ H1f, int cap)
{
    const int cnt = (*cntp < cap) ? *cntp : cap;
    const int total = cnt * 400;
    const size_t cs = (size_t)cap * 400;
    for (int i = blockIdx.x * 256 + threadIdx.x; i < total;
         i += gridDim.x * 256) {
        const int j = i % 400;
        double s = (double)b1[j];
        #pragma unroll
        for (int c = 0; c < 6; ++c) s += Part[c * cs + i];
        H1f[i] = s > 0.0 ? s : 0.0;
    }
}

// ======= fixup F3: exact f64 distances + argmin + z_q scatter ===============
__global__ __launch_bounds__(512) void fix_argmin(
    const double* __restrict__ Zf, const float* __restrict__ Wemb,
    const int* __restrict__ cntp, const int* __restrict__ ids,
    float* __restrict__ zq, int cap)
{
    __shared__ float  wesh[16384];      // 64 KB
    __shared__ double zsh[4][1032];     // 33 KB (pad)
    __shared__ double dist[4 * 8 * 128];// 32 KB
    __shared__ int    idxf[32];

    const int tid  = threadIdx.x;
    const int lane = tid & 63;
    const int wv   = tid >> 6;
    const int cnt  = (*cntp < cap) ? *cntp : cap;
    const int base = blockIdx.x * 4;
    if (base >= cnt) return;
    const int ns = (cnt - base < 4) ? (cnt - base) : 4;

    for (int i = tid; i < 4096; i += 512)
        reinterpret_cast<float4*>(wesh)[i] =
            reinterpret_cast<const float4*>(Wemb)[i];
    for (int i = tid; i < 4 * 512; i += 512) {
        const int s = i >> 9, e = (i & 511) * 2;
        if (s < ns) {
            const double2 v = *reinterpret_cast<const double2*>(
                &Zf[(size_t)(base + s) * 1024 + e]);
            zsh[s][e] = v.x;
            zsh[s][e + 1] = v.y;
        }
    }
    __syncthreads();

    for (int t = tid; t < ns * 1024; t += 512) {
        const int s = t >> 10, d = (t >> 7) & 7, n = t & 127;
        double acc = 0.0;
        for (int k = 0; k < 128; ++k) {
            const double diff = zsh[s][k * 8 + d] - (double)wesh[k * 128 + n];
            acc = fma(diff, diff, acc);
        }
        dist[(s * 8 + d) * 128 + n] = acc;
    }
    __syncthreads();

    for (int p = wv; p < ns * 8; p += 8) {
        const double* dp = &dist[p * 128];
        double v0 = dp[lane], vx = dp[lane + 64];
        double v; int ix;
        if (vx < v0) { v = vx; ix = lane + 64; }
        else         { v = v0; ix = lane; }
        #pragma unroll
        for (int off = 32; off > 0; off >>= 1) {
            const double ov = __shfl_down(v, off);
            const int    oi = __shfl_down(ix, off);
            if (ov < v || (ov == v && oi < ix)) { v = ov; ix = oi; }
        }
        if (lane == 0) idxf[p] = ix;
    }
    __syncthreads();

    for (int i = tid; i < ns * 1024; i += 512) {
        const int s = i >> 10, ii = i & 1023;
        zq[(size_t)ids[base + s] * 1024 + ii] =
            wesh[(ii >> 3) * 128 + idxf[s * 8 + (ii & 7)]];
    }
}

// ---------------------------------------------------------------------------
extern "C" void kernel_launch(void* const* d_in, const int* in_sizes, int n_in,
                              void* d_out, int out_size, void* d_ws, size_t ws_size,
                              hipStream_t stream)
{
    const float* x    = (const float*)d_in[0];
    const float* W1   = (const float*)d_in[1];
    const float* b1   = (const float*)d_in[2];
    const float* W2   = (const float*)d_in[3];
    const float* b2   = (const float*)d_in[4];
    const float* W3   = (const float*)d_in[5];
    const float* b3   = (const float*)d_in[6];
    const float* W4   = (const float*)d_in[7];
    const float* b4   = (const float*)d_in[8];
    const float* Wemb = (const float*)d_in[9];

    const int B = 16384;
    float* out   = (float*)d_out;
    float* recon = out;                                // B*3072
    float* z_e   = out + (size_t)B * 3072;             // B*1024
    float* emb_o = z_e + (size_t)B * 1024;             // B*1024 == z_q

    constexpr size_t X_PL  = 50331648;
    constexpr size_t H1_PL = 6815744;
    constexpr size_t H3_PL = 6815744;
    constexpr size_t W1_PL = 1572864;
    constexpr size_t W2_PL = 425984;
    constexpr size_t W3_PL = 524288;
    constexpr size_t W4_PL = 1277952;

    short* xh  = (short*)recon;
    short* xl  = xh + X_PL;
    short* h1h = (short*)emb_o;
    short* h1l = h1h + H1_PL;

    short*  h3h      = (short*)d_ws;
    short*  w1h      = h3h + H3_PL;
    short*  w1l      = w1h + W1_PL;
    short*  w2h      = w1l + W1_PL;
    short*  w2l      = w2h + W2_PL;
    short*  w3h      = w2l + W2_PL;
    short*  w4h      = w3h + W3_PL;
    short*  wembpl   = w4h + W4_PL;
    double* wn       = (double*)(wembpl + 32768);
    int*    flag_cnt = (int*)(wn + 128);
    int*    flag_ids = flag_cnt + 64;

    // fixup scratch in the recon section (x-planes dead after g1; g4 writes
    // recon last): Part[6] @ +0, H1f @ +80MB, Zf @ +96MB  (ends ~129.5MB)
    char*   scr  = (char*)recon;
    double* Part = (double*)scr;                       // 6*4096*400*8 = 78.6MB
    double* H1f  = (double*)(scr + (80ull  << 20));    // 13.1MB
    double* Zf   = (double*)(scr + (96ull  << 20));    // 33.5MB

    prep_wplanes<<<dim3(384), dim3(256), 0, stream>>>(W1, 400, 3072, 96, w1h, w1l);
    prep_wplanes<<<dim3(104), dim3(256), 0, stream>>>(W2, 1024, 400, 13, w2h, w2l);
    prep_wplanes<<<dim3(128), dim3(256), 0, stream>>>(W3, 400, 1024, 32, w3h, nullptr);
    prep_wplanes<<<dim3(312), dim3(256), 0, stream>>>(W4, 3072, 400, 13, w4h, nullptr);
    prep_xplanes<<<dim3(12288), dim3(256), 0, stream>>>(x, xh, xl);
    vq_prep<<<dim3(1), dim3(256), 0, stream>>>(Wemb, wembpl, wn, flag_cnt);

    gemm_pl<2, 1, 0, 2><<<dim3(4, 128), dim3(256), 0, stream>>>(
        xh, xl, nullptr, 0, w1h, w1l, b1, nullptr, h1h, h1l, 400, 96, 13);
    gemm_pl<2, 0, 0, 0><<<dim3(8, 128), dim3(256), 0, stream>>>(
        h1h, h1l, nullptr, 0, w2h, w2l, b2, z_e, nullptr, nullptr, 1024, 13, 0);

    vq_mfma<<<dim3(1024), dim3(512), 0, stream>>>(z_e, wembpl, wn, emb_o,
                                                  flag_cnt, flag_ids);

    // ---- exact fixup pipeline (tiled f64 GEMMs over flagged samples) ----
    // F1: Part[c] = gatherX @ W1^T  (K=3072 in 6 chunks of 512)
    gemm_f64t<true, true, float><<<dim3(7, FIX_CAP / 64, 6), dim3(256), 0, stream>>>(
        x, W1, flag_ids, flag_cnt, nullptr, Part, 3072, 400, 400, 512, FIX_CAP);
    // FR: H1f = relu(sum Part + b1)
    fix_reduce<<<dim3(512), dim3(256), 0, stream>>>(Part, b1, flag_cnt, H1f, FIX_CAP);
    // F2: Zf = H1f @ W2^T + b2
    gemm_f64t<false, false, double><<<dim3(16, FIX_CAP / 64), dim3(256), 0, stream>>>(
        H1f, W2, nullptr, flag_cnt, b2, Zf, 400, 1024, 1024, 400, FIX_CAP);
    // F3: exact distances + argmin + scatter
    fix_argmin<<<dim3(FIX_CAP / 4), dim3(512), 0, stream>>>(
        Zf, Wemb, flag_cnt, flag_ids, emb_o, FIX_CAP);

    gemm_pl<1, 1, 1, 1><<<dim3(4, 128), dim3(256), 0, stream>>>(
        nullptr, nullptr, emb_o, 1024, w3h, nullptr, b3, nullptr, h3h, nullptr,
        400, 32, 13);
    gemm_pl<1, 2, 0, 0><<<dim3(24, 128), dim3(256), 0, stream>>>(
        h3h, nullptr, nullptr, 0, w4h, nullptr, b4, recon, nullptr, nullptr,
        3072, 13, 0);
}